// Round 6
// baseline (180.214 us; speedup 1.0000x reference)
//
#include <hip/hip_runtime.h>

#define NROWS 4096
#define DIM   512
#define MARGIN 0.2f
#define EPS 1e-6f
#define BIG 1e9f
#define NBLOCKS 528             // 32*33/2 triangle tiles of 128x128
#define BPX 66                  // NBLOCKS / 8 (XCD swizzle)

typedef __attribute__((ext_vector_type(8))) short bf16x8;
typedef __attribute__((ext_vector_type(4))) float f32x4;

// monotone float <-> uint mapping (order-preserving), for atomicMax/Min on floats
__device__ __forceinline__ unsigned enc_f(float x) {
    unsigned u = __float_as_uint(x);
    return (u & 0x80000000u) ? ~u : (u | 0x80000000u);
}
__device__ __forceinline__ float dec_f(unsigned u) {
    return (u & 0x80000000u) ? __uint_as_float(u ^ 0x80000000u) : __uint_as_float(~u);
}

// RNE f32->bf16 (identical math to the R2-R5 prep kernel; absmax 0.0 proven)
__device__ __forceinline__ unsigned short f2bf_rne(float x) {
    unsigned u = __float_as_uint(x);
    unsigned r = u + 0x7FFFu + ((u >> 16) & 1u);
    return (unsigned short)(r >> 16);
}

__global__ void init_kernel(unsigned* __restrict__ hp, unsigned* __restrict__ hn,
                            unsigned* __restrict__ counter) {
    int i = blockIdx.x * blockDim.x + threadIdx.x;
    if (i < NROWS) {
        hp[i] = enc_f(-BIG);
        hn[i] = enc_f(BIG);
    }
    if (i == 0) *counter = 0u;
}

#define AS1(p) ((const __attribute__((address_space(1))) unsigned int*)(p))
#define AS3(p) ((__attribute__((address_space(3))) unsigned int*)(p))

__device__ __forceinline__ void gll16(const float* g, float* l) {
    __builtin_amdgcn_global_load_lds(AS1(g), AS3(l), 16, 0, 0);
}

// split 8 f32 (two f32x4) into bf16 hi + lo fragments (in-register)
__device__ __forceinline__ void cvt_hilo(const f32x4 x0, const f32x4 x1,
                                         bf16x8* hi, bf16x8* lo) {
    bf16x8 h, l;
#pragma unroll
    for (int e = 0; e < 4; e++) {
        const float x = x0[e];
        const unsigned short hu = f2bf_rne(x);
        const float hf = __uint_as_float((unsigned)hu << 16);
        h[e] = (short)hu;
        l[e] = (short)f2bf_rne(x - hf);
    }
#pragma unroll
    for (int e = 0; e < 4; e++) {
        const float x = x1[e];
        const unsigned short hu = f2bf_rne(x);
        const float hf = __uint_as_float((unsigned)hu << 16);
        h[4 + e] = (short)hu;
        l[4 + e] = (short)f2bf_rne(x - hf);
    }
    *hi = h;
    *lo = l;
}

// Fused bf16x3 Gram GEMM + batch-hard mining, lower-triangle 128x128 tiles.
// R6: stage f32 feats directly (no prep, ws = 33KB) into 64KB double-buffered
// LDS; counted-vmcnt loop (vmcnt(8) per step, never 0 until epilogue) with raw
// s_barrier so next-tile loads stay in flight across barriers (T3/T4).
// 16B-chunk XOR swizzle c^=(row&7) on source + reads -> 2 lanes/bank (free).
// hi/lo bf16 split in-register (VALU pipe is idle); MFMA order identical to R3.
__launch_bounds__(256, 2)
__global__ void gram_mine_kernel(const float* __restrict__ feats,
                                 const int* __restrict__ labels,
                                 unsigned* __restrict__ hp,
                                 unsigned* __restrict__ hn,
                                 unsigned* __restrict__ counter,
                                 float* __restrict__ out) {
    __shared__ __align__(16) float As[2][128][32];
    __shared__ __align__(16) float Bs[2][128][32];

    const int tid = threadIdx.x;
    const int lane = tid & 63;
    const int w = tid >> 6;        // wave 0..3
    const int wm = w >> 1;         // wave row 0..1
    const int wn = w & 1;          // wave col 0..1

    // XCD-aware bijective swizzle (528 = 8*66), then triangle unrank (bx <= by)
    const int bid = blockIdx.x;
    const int t0 = (bid & 7) * BPX + (bid >> 3);
    int by = (int)((sqrtf(8.0f * (float)t0 + 1.0f) - 1.0f) * 0.5f);
    while ((by + 1) * (by + 2) / 2 <= t0) by++;
    while (by * (by + 1) / 2 > t0) by--;
    const int bx = t0 - by * (by + 1) / 2;
    const int r0 = by * 128;
    const int c0 = bx * 128;
    const bool offdiag = (by != bx);

    // staging: per gll16, lane l -> LDS row (l>>3) of an 8-row group, 16B chunk
    // (l&7) [linear dest]; source chunk pre-swizzled: phys chunk s of row r
    // holds logical chunk s^(r&7). Wave w stages rows [32w, 32w+32) of A and B,
    // 4 gll16 each -> 8 gll16 per wave per K-step (the vmcnt(8) unit).
    const int srow8 = lane >> 3;                      // 0..7
    const int scol = ((lane & 7) ^ srow8) * 4;        // swizzled source chunk (floats)

#define STAGE(buf, kt)                                                                  \
    {                                                                                   \
        const int k0 = (kt) * 32;                                                       \
        _Pragma("unroll")                                                               \
        for (int q = 0; q < 4; q++) {                                                   \
            const int rr = 32 * w + 8 * q + srow8;                                      \
            gll16(&feats[(size_t)(r0 + rr) * DIM + k0 + scol],                          \
                  &As[buf][32 * w + 8 * q][0] + lane * 4);                              \
            gll16(&feats[(size_t)(c0 + rr) * DIM + k0 + scol],                          \
                  &Bs[buf][32 * w + 8 * q][0] + lane * 4);                              \
        }                                                                               \
    }

    const int frow = lane & 15;     // fragment row/col within 16
    const int fkg = lane >> 4;      // k-group 0..3 (8 floats each)
    const int pc0 = ((2 * fkg) ^ (frow & 7)) * 4;       // phys chunk of k 0..3 (floats)
    const int pc1 = ((2 * fkg + 1) ^ (frow & 7)) * 4;   // phys chunk of k 4..7

    f32x4 acc[4][4];
#pragma unroll
    for (int i = 0; i < 4; i++)
#pragma unroll
        for (int j = 0; j < 4; j++) acc[i][j] = (f32x4)(0.0f);

#define DSREAD(buf, AF, BF)                                                             \
    {                                                                                   \
        _Pragma("unroll")                                                               \
        for (int mi = 0; mi < 4; mi++) {                                                \
            const float* rowp = &As[buf][wm * 64 + mi * 16 + frow][0];                  \
            AF[mi][0] = *(const f32x4*)(rowp + pc0);                                    \
            AF[mi][1] = *(const f32x4*)(rowp + pc1);                                    \
        }                                                                               \
        _Pragma("unroll")                                                               \
        for (int nj = 0; nj < 4; nj++) {                                                \
            const float* rowp = &Bs[buf][wn * 64 + nj * 16 + frow][0];                  \
            BF[nj][0] = *(const f32x4*)(rowp + pc0);                                    \
            BF[nj][1] = *(const f32x4*)(rowp + pc1);                                    \
        }                                                                               \
    }

#define CVT_MFMA(AF, BF)                                                                \
    {                                                                                   \
        bf16x8 ah[4], al[4], bh[4], bl[4];                                              \
        _Pragma("unroll")                                                               \
        for (int mi = 0; mi < 4; mi++) cvt_hilo(AF[mi][0], AF[mi][1], &ah[mi], &al[mi]); \
        _Pragma("unroll")                                                               \
        for (int nj = 0; nj < 4; nj++) cvt_hilo(BF[nj][0], BF[nj][1], &bh[nj], &bl[nj]); \
        _Pragma("unroll")                                                               \
        for (int mi = 0; mi < 4; mi++)                                                  \
            _Pragma("unroll")                                                           \
            for (int nj = 0; nj < 4; nj++)                                              \
                acc[mi][nj] = __builtin_amdgcn_mfma_f32_16x16x32_bf16(ah[mi], bh[nj],   \
                                                                      acc[mi][nj], 0, 0, 0); \
        _Pragma("unroll")                                                               \
        for (int mi = 0; mi < 4; mi++)                                                  \
            _Pragma("unroll")                                                           \
            for (int nj = 0; nj < 4; nj++)                                              \
                acc[mi][nj] = __builtin_amdgcn_mfma_f32_16x16x32_bf16(ah[mi], bl[nj],   \
                                                                      acc[mi][nj], 0, 0, 0); \
        _Pragma("unroll")                                                               \
        for (int mi = 0; mi < 4; mi++)                                                  \
            _Pragma("unroll")                                                           \
            for (int nj = 0; nj < 4; nj++)                                              \
                acc[mi][nj] = __builtin_amdgcn_mfma_f32_16x16x32_bf16(al[mi], bh[nj],   \
                                                                      acc[mi][nj], 0, 0, 0); \
    }

    STAGE(0, 0)
    STAGE(1, 1)
    // invariant: 16 gll16 outstanding (tiles t, t+1) at each loop top

    for (int t = 0; t < 15; ++t) {
        asm volatile("s_waitcnt vmcnt(8)" ::: "memory");   // tile t landed (mine)
        __builtin_amdgcn_s_barrier();                      // ... and everyone's
        __builtin_amdgcn_sched_barrier(0);

        f32x4 af[4][2], bf[4][2];
        DSREAD(t & 1, af, bf)
        asm volatile("s_waitcnt lgkmcnt(0)" ::: "memory"); // my reads done
        __builtin_amdgcn_sched_barrier(0);
        __builtin_amdgcn_s_barrier();                      // everyone done reading
        __builtin_amdgcn_sched_barrier(0);

        if (t <= 13) STAGE(t & 1, t + 2)                   // overwrite freed buffer
        CVT_MFMA(af, bf)
    }
    // epilogue: tile 15 (buffer 1), only 8 loads outstanding
    asm volatile("s_waitcnt vmcnt(0)" ::: "memory");
    __builtin_amdgcn_s_barrier();
    __builtin_amdgcn_sched_barrier(0);
    {
        f32x4 af[4][2], bf[4][2];
        DSREAD(1, af, bf)
        asm volatile("s_waitcnt lgkmcnt(0)" ::: "memory");
        __builtin_amdgcn_sched_barrier(0);
        CVT_MFMA(af, bf)
    }

    // ---- fused batch-hard mining (C frag: col = frow, row = fkg*4 + reg) ----
    int rlab[4][4], clab[4];
#pragma unroll
    for (int mi = 0; mi < 4; mi++)
#pragma unroll
        for (int rg = 0; rg < 4; rg++)
            rlab[mi][rg] = labels[r0 + wm * 64 + mi * 16 + fkg * 4 + rg];
#pragma unroll
    for (int nj = 0; nj < 4; nj++)
        clab[nj] = labels[c0 + wn * 64 + nj * 16 + frow];

    float pmax[4][4], nmin[4][4];   // row-anchor
    float cpmax[4], cnmin[4];       // col-anchor (symmetric pass)
#pragma unroll
    for (int mi = 0; mi < 4; mi++)
#pragma unroll
        for (int rg = 0; rg < 4; rg++) { pmax[mi][rg] = -BIG; nmin[mi][rg] = BIG; }
#pragma unroll
    for (int nj = 0; nj < 4; nj++) { cpmax[nj] = -BIG; cnmin[nj] = BIG; }

#pragma unroll
    for (int mi = 0; mi < 4; mi++)
#pragma unroll
        for (int nj = 0; nj < 4; nj++)
#pragma unroll
            for (int rg = 0; rg < 4; rg++) {
                const float dist = 1.0f - acc[mi][nj][rg];
                if (rlab[mi][rg] == clab[nj]) {
                    if (dist > EPS) {
                        pmax[mi][rg] = fmaxf(pmax[mi][rg], dist);
                        cpmax[nj] = fmaxf(cpmax[nj], dist);
                    }
                } else {
                    nmin[mi][rg] = fminf(nmin[mi][rg], dist);
                    cnmin[nj] = fminf(cnmin[nj], dist);
                }
            }

    // row-anchor reduce across 16 cols (lanes with same fkg)
#pragma unroll
    for (int off = 8; off; off >>= 1) {
#pragma unroll
        for (int mi = 0; mi < 4; mi++)
#pragma unroll
            for (int rg = 0; rg < 4; rg++) {
                pmax[mi][rg] = fmaxf(pmax[mi][rg], __shfl_xor(pmax[mi][rg], off, 16));
                nmin[mi][rg] = fminf(nmin[mi][rg], __shfl_xor(nmin[mi][rg], off, 16));
            }
    }
    if (frow == 0) {
#pragma unroll
        for (int mi = 0; mi < 4; mi++)
#pragma unroll
            for (int rg = 0; rg < 4; rg++) {
                const int R = r0 + wm * 64 + mi * 16 + fkg * 4 + rg;
                atomicMax(&hp[R], enc_f(pmax[mi][rg]));
                atomicMin(&hn[R], enc_f(nmin[mi][rg]));
            }
    }

    // col-anchor reduce across the 16 rows (xor 16, 32); skip on diagonal
    if (offdiag) {
#pragma unroll
        for (int nj = 0; nj < 4; nj++) {
            cpmax[nj] = fmaxf(cpmax[nj], __shfl_xor(cpmax[nj], 16, 64));
            cpmax[nj] = fmaxf(cpmax[nj], __shfl_xor(cpmax[nj], 32, 64));
            cnmin[nj] = fminf(cnmin[nj], __shfl_xor(cnmin[nj], 16, 64));
            cnmin[nj] = fminf(cnmin[nj], __shfl_xor(cnmin[nj], 32, 64));
        }
        if (fkg == 0) {
#pragma unroll
            for (int nj = 0; nj < 4; nj++) {
                const int C = c0 + wn * 64 + nj * 16 + frow;
                atomicMax(&hp[C], enc_f(cpmax[nj]));
                atomicMin(&hn[C], enc_f(cnmin[nj]));
            }
        }
    }

    // ---- last-block finalize (device-scope counter) ----
    __threadfence();
    __syncthreads();
    __shared__ unsigned sold;
    if (tid == 0) sold = atomicAdd(counter, 1u);
    __syncthreads();
    if (sold == NBLOCKS - 1 && tid < 64) {
        __threadfence();
        float sum = 0.0f;
        int cnt = 0;
        for (int i = tid; i < NROWS; i += 64) {
            const float p = dec_f(__hip_atomic_load(&hp[i], __ATOMIC_RELAXED, __HIP_MEMORY_SCOPE_AGENT));
            const float n = dec_f(__hip_atomic_load(&hn[i], __ATOMIC_RELAXED, __HIP_MEMORY_SCOPE_AGENT));
            const float tl = p - n + MARGIN;
            if (tl > 0.0f) { sum += tl; cnt++; }
        }
#pragma unroll
        for (int off = 32; off; off >>= 1) {
            sum += __shfl_down(sum, off, 64);
            cnt += __shfl_down(cnt, off, 64);
        }
        if (tid == 0) out[0] = (cnt > 0) ? sum / (float)cnt : 0.0f;
    }
#undef STAGE
#undef DSREAD
#undef CVT_MFMA
}

extern "C" void kernel_launch(void* const* d_in, const int* in_sizes, int n_in,
                              void* d_out, int out_size, void* d_ws, size_t ws_size,
                              hipStream_t stream) {
    const float* feats = (const float*)d_in[0];
    const int* labels = (const int*)d_in[1];
    float* out = (float*)d_out;

    unsigned* hp = (unsigned*)d_ws;        // 4096 u32
    unsigned* hn = hp + NROWS;             // 4096 u32
    unsigned* counter = hn + NROWS;        // 1 u32   (total ws use: ~33KB)

    init_kernel<<<16, 256, 0, stream>>>(hp, hn, counter);
    gram_mine_kernel<<<NBLOCKS, 256, 0, stream>>>(feats, labels, hp, hn, counter, out);
}

// Round 7
// 156.890 us; speedup vs baseline: 1.1487x; 1.1487x over previous
//
#include <hip/hip_runtime.h>

#define NROWS 4096
#define DIM   512
#define MARGIN 0.2f
#define EPS 1e-6f
#define BIG 1e9f
#define NBLOCKS 528             // 32*33/2 triangle tiles of 128x128
#define BPX 66                  // NBLOCKS / 8 (XCD swizzle)

typedef __attribute__((ext_vector_type(8))) short bf16x8;
typedef __attribute__((ext_vector_type(4))) float f32x4;

// monotone float <-> uint mapping (order-preserving), for atomicMax/Min on floats
__device__ __forceinline__ unsigned enc_f(float x) {
    unsigned u = __float_as_uint(x);
    return (u & 0x80000000u) ? ~u : (u | 0x80000000u);
}
__device__ __forceinline__ float dec_f(unsigned u) {
    return (u & 0x80000000u) ? __uint_as_float(u ^ 0x80000000u) : __uint_as_float(~u);
}

__device__ __forceinline__ unsigned short f2bf_rne(float x) {
    unsigned u = __float_as_uint(x);
    unsigned r = u + 0x7FFFu + ((u >> 16) & 1u);
    return (unsigned short)(r >> 16);
}

// split f32 feats into bf16 hi + lo; also init hp/hn and the done-counter
__global__ void prep_kernel(const float* __restrict__ feats,
                            unsigned short* __restrict__ fhi,
                            unsigned short* __restrict__ flo,
                            unsigned* __restrict__ hp,
                            unsigned* __restrict__ hn,
                            unsigned* __restrict__ counter) {
    const int gid = blockIdx.x * 256 + threadIdx.x;
    if (gid < NROWS) {
        hp[gid] = enc_f(-BIG);
        hn[gid] = enc_f(BIG);
    }
    if (gid == 0) *counter = 0u;
    const int i = gid * 4;
    const float4 v = *(const float4*)&feats[i];
    float x[4] = {v.x, v.y, v.z, v.w};
    unsigned short h[4], l[4];
#pragma unroll
    for (int j = 0; j < 4; j++) {
        h[j] = f2bf_rne(x[j]);
        const float hf = __uint_as_float(((unsigned)h[j]) << 16);
        l[j] = f2bf_rne(x[j] - hf);
    }
    *(ushort4*)&fhi[i] = make_ushort4(h[0], h[1], h[2], h[3]);
    *(ushort4*)&flo[i] = make_ushort4(l[0], l[1], l[2], l[3]);
}

#define AS1(p) ((const __attribute__((address_space(1))) unsigned int*)(p))
#define AS3(p) ((__attribute__((address_space(3))) unsigned int*)(p))

__device__ __forceinline__ void gll16(const unsigned short* g, unsigned short* l) {
    __builtin_amdgcn_global_load_lds(AS1(g), AS3(l), 16, 0, 0);
}

// Fused bf16x3 Gram GEMM + batch-hard mining, lower-triangle 128x128 tiles.
// R7 = R3 data path (proven 65us, 0 conflicts, bit-identical math) with the
// sync structure replaced by counted-vmcnt (T4): per K-step wait vmcnt(8) so
// the next tile's 8 gll16 stay in flight across both barriers; vmcnt(0) only
// at the final tile. s_setprio(1) around the MFMA cluster (T5).
__launch_bounds__(256, 2)
__global__ void gram_mine_kernel(const unsigned short* __restrict__ fhi,
                                 const unsigned short* __restrict__ flo,
                                 const int* __restrict__ labels,
                                 unsigned* __restrict__ hp,
                                 unsigned* __restrict__ hn,
                                 unsigned* __restrict__ counter,
                                 float* __restrict__ out) {
    __shared__ __align__(16) unsigned short As_hi[2][128][32];
    __shared__ __align__(16) unsigned short As_lo[2][128][32];
    __shared__ __align__(16) unsigned short Bs_hi[2][128][32];
    __shared__ __align__(16) unsigned short Bs_lo[2][128][32];
    __shared__ unsigned sold;

    const int tid = threadIdx.x;
    const int lane = tid & 63;
    const int w = tid >> 6;        // wave 0..3
    const int wm = w >> 1;         // wave row 0..1
    const int wn = w & 1;          // wave col 0..1

    // XCD-aware bijective swizzle (528 = 8*66), then triangle unrank (bx <= by)
    const int bid = blockIdx.x;
    const int t0 = (bid & 7) * BPX + (bid >> 3);
    int by = (int)((sqrtf(8.0f * (float)t0 + 1.0f) - 1.0f) * 0.5f);
    while ((by + 1) * (by + 2) / 2 <= t0) by++;
    while (by * (by + 1) / 2 > t0) by--;
    const int bx = t0 - by * (by + 1) / 2;
    const int r0 = by * 128;
    const int c0 = bx * 128;
    const bool offdiag = (by != bx);

    // staging (R3-proven): lane l -> LDS row 16q+(l>>2), 16B slot (l&3) linear;
    // source chunk pre-swizzled: phys slot s of row r holds chunk s^((r>>1)&3)
    const int srow = lane >> 2;
    const int scol = ((lane & 3) ^ ((lane >> 3) & 3)) * 8;

// 8 gll16 per wave per STAGE (the vmcnt(8) accounting unit)
#define STAGE(buf, kt)                                                                  \
    {                                                                                   \
        const int k0 = (kt) * 32;                                                       \
        _Pragma("unroll")                                                               \
        for (int q = 0; q < 2; q++) {                                                   \
            const int rr = 32 * w + 16 * q + srow;                                      \
            gll16(&fhi[(size_t)(r0 + rr) * DIM + k0 + scol],                            \
                  &As_hi[buf][32 * w + 16 * q][0] + lane * 8);                          \
            gll16(&flo[(size_t)(r0 + rr) * DIM + k0 + scol],                            \
                  &As_lo[buf][32 * w + 16 * q][0] + lane * 8);                          \
            gll16(&fhi[(size_t)(c0 + rr) * DIM + k0 + scol],                            \
                  &Bs_hi[buf][32 * w + 16 * q][0] + lane * 8);                          \
            gll16(&flo[(size_t)(c0 + rr) * DIM + k0 + scol],                            \
                  &Bs_lo[buf][32 * w + 16 * q][0] + lane * 8);                          \
        }                                                                               \
    }

    const int frow = lane & 15;     // fragment row/col within 16
    const int fkg = lane >> 4;      // k-group 0..3 (8 bf16 each)
    const int ch = (fkg ^ ((frow >> 1) & 3)) * 8;   // swizzled read chunk

    f32x4 acc[4][4];
#pragma unroll
    for (int i = 0; i < 4; i++)
#pragma unroll
        for (int j = 0; j < 4; j++) acc[i][j] = (f32x4)(0.0f);

#define DSREAD(buf, AH, AL, BH, BL)                                                     \
    {                                                                                   \
        _Pragma("unroll")                                                               \
        for (int mi = 0; mi < 4; mi++) {                                                \
            const int r = wm * 64 + mi * 16 + frow;                                     \
            AH[mi] = *(const bf16x8*)&As_hi[buf][r][ch];                                \
            AL[mi] = *(const bf16x8*)&As_lo[buf][r][ch];                                \
        }                                                                               \
        _Pragma("unroll")                                                               \
        for (int nj = 0; nj < 4; nj++) {                                                \
            const int c = wn * 64 + nj * 16 + frow;                                     \
            BH[nj] = *(const bf16x8*)&Bs_hi[buf][c][ch];                                \
            BL[nj] = *(const bf16x8*)&Bs_lo[buf][c][ch];                                \
        }                                                                               \
    }

#define MFMA3(AH, AL, BH, BL)                                                           \
    {                                                                                   \
        __builtin_amdgcn_s_setprio(1);                                                  \
        _Pragma("unroll")                                                               \
        for (int mi = 0; mi < 4; mi++)                                                  \
            _Pragma("unroll")                                                           \
            for (int nj = 0; nj < 4; nj++)                                              \
                acc[mi][nj] = __builtin_amdgcn_mfma_f32_16x16x32_bf16(AH[mi], BH[nj],   \
                                                                      acc[mi][nj], 0, 0, 0); \
        _Pragma("unroll")                                                               \
        for (int mi = 0; mi < 4; mi++)                                                  \
            _Pragma("unroll")                                                           \
            for (int nj = 0; nj < 4; nj++)                                              \
                acc[mi][nj] = __builtin_amdgcn_mfma_f32_16x16x32_bf16(AH[mi], BL[nj],   \
                                                                      acc[mi][nj], 0, 0, 0); \
        _Pragma("unroll")                                                               \
        for (int mi = 0; mi < 4; mi++)                                                  \
            _Pragma("unroll")                                                           \
            for (int nj = 0; nj < 4; nj++)                                              \
                acc[mi][nj] = __builtin_amdgcn_mfma_f32_16x16x32_bf16(AL[mi], BH[nj],   \
                                                                      acc[mi][nj], 0, 0, 0); \
        __builtin_amdgcn_s_setprio(0);                                                  \
    }

    STAGE(0, 0)
    STAGE(1, 1)
    // invariant at loop top: 16 gll16 outstanding (tiles t, t+1)

    for (int t = 0; t < 15; ++t) {
        asm volatile("s_waitcnt vmcnt(8)" ::: "memory");   // my tile-t loads landed
        __builtin_amdgcn_sched_barrier(0);
        __builtin_amdgcn_s_barrier();                      // everyone's landed
        __builtin_amdgcn_sched_barrier(0);

        bf16x8 ah[4], al[4], bh[4], bl[4];
        DSREAD(t & 1, ah, al, bh, bl)
        asm volatile("s_waitcnt lgkmcnt(0)" ::: "memory"); // my frags in regs
        __builtin_amdgcn_sched_barrier(0);
        __builtin_amdgcn_s_barrier();                      // all done reading buf
        __builtin_amdgcn_sched_barrier(0);

        if (t <= 13) STAGE(t & 1, t + 2)                   // refill freed buffer
        MFMA3(ah, al, bh, bl)
    }
    // final tile 15 (buffer 1): only 8 loads outstanding -> full drain once
    asm volatile("s_waitcnt vmcnt(0)" ::: "memory");
    __builtin_amdgcn_sched_barrier(0);
    __builtin_amdgcn_s_barrier();
    __builtin_amdgcn_sched_barrier(0);
    {
        bf16x8 ah[4], al[4], bh[4], bl[4];
        DSREAD(1, ah, al, bh, bl)
        asm volatile("s_waitcnt lgkmcnt(0)" ::: "memory");
        __builtin_amdgcn_sched_barrier(0);
        MFMA3(ah, al, bh, bl)
    }

    // ---- fused batch-hard mining (C frag: col = frow, row = fkg*4 + reg) ----
    int rlab[4][4], clab[4];
#pragma unroll
    for (int mi = 0; mi < 4; mi++)
#pragma unroll
        for (int rg = 0; rg < 4; rg++)
            rlab[mi][rg] = labels[r0 + wm * 64 + mi * 16 + fkg * 4 + rg];
#pragma unroll
    for (int nj = 0; nj < 4; nj++)
        clab[nj] = labels[c0 + wn * 64 + nj * 16 + frow];

    float pmax[4][4], nmin[4][4];   // row-anchor
    float cpmax[4], cnmin[4];       // col-anchor (symmetric pass)
#pragma unroll
    for (int mi = 0; mi < 4; mi++)
#pragma unroll
        for (int rg = 0; rg < 4; rg++) { pmax[mi][rg] = -BIG; nmin[mi][rg] = BIG; }
#pragma unroll
    for (int nj = 0; nj < 4; nj++) { cpmax[nj] = -BIG; cnmin[nj] = BIG; }

#pragma unroll
    for (int mi = 0; mi < 4; mi++)
#pragma unroll
        for (int nj = 0; nj < 4; nj++)
#pragma unroll
            for (int rg = 0; rg < 4; rg++) {
                const float dist = 1.0f - acc[mi][nj][rg];
                if (rlab[mi][rg] == clab[nj]) {
                    if (dist > EPS) {
                        pmax[mi][rg] = fmaxf(pmax[mi][rg], dist);
                        cpmax[nj] = fmaxf(cpmax[nj], dist);
                    }
                } else {
                    nmin[mi][rg] = fminf(nmin[mi][rg], dist);
                    cnmin[nj] = fminf(cnmin[nj], dist);
                }
            }

    // row-anchor reduce across 16 cols (lanes with same fkg)
#pragma unroll
    for (int off = 8; off; off >>= 1) {
#pragma unroll
        for (int mi = 0; mi < 4; mi++)
#pragma unroll
            for (int rg = 0; rg < 4; rg++) {
                pmax[mi][rg] = fmaxf(pmax[mi][rg], __shfl_xor(pmax[mi][rg], off, 16));
                nmin[mi][rg] = fminf(nmin[mi][rg], __shfl_xor(nmin[mi][rg], off, 16));
            }
    }
    if (frow == 0) {
#pragma unroll
        for (int mi = 0; mi < 4; mi++)
#pragma unroll
            for (int rg = 0; rg < 4; rg++) {
                const int R = r0 + wm * 64 + mi * 16 + fkg * 4 + rg;
                atomicMax(&hp[R], enc_f(pmax[mi][rg]));
                atomicMin(&hn[R], enc_f(nmin[mi][rg]));
            }
    }

    // col-anchor reduce across the 16 rows (xor 16, 32); skip on diagonal
    if (offdiag) {
#pragma unroll
        for (int nj = 0; nj < 4; nj++) {
            cpmax[nj] = fmaxf(cpmax[nj], __shfl_xor(cpmax[nj], 16, 64));
            cpmax[nj] = fmaxf(cpmax[nj], __shfl_xor(cpmax[nj], 32, 64));
            cnmin[nj] = fminf(cnmin[nj], __shfl_xor(cnmin[nj], 16, 64));
            cnmin[nj] = fminf(cnmin[nj], __shfl_xor(cnmin[nj], 32, 64));
        }
        if (fkg == 0) {
#pragma unroll
            for (int nj = 0; nj < 4; nj++) {
                const int C = c0 + wn * 64 + nj * 16 + frow;
                atomicMax(&hp[C], enc_f(cpmax[nj]));
                atomicMin(&hn[C], enc_f(cnmin[nj]));
            }
        }
    }

    // ---- last-block finalize (device-scope counter) ----
    __threadfence();
    __syncthreads();
    if (tid == 0) sold = atomicAdd(counter, 1u);
    __syncthreads();
    if (sold == NBLOCKS - 1 && tid < 64) {
        __threadfence();
        float sum = 0.0f;
        int cnt = 0;
        for (int i = tid; i < NROWS; i += 64) {
            const float p = dec_f(__hip_atomic_load(&hp[i], __ATOMIC_RELAXED, __HIP_MEMORY_SCOPE_AGENT));
            const float n = dec_f(__hip_atomic_load(&hn[i], __ATOMIC_RELAXED, __HIP_MEMORY_SCOPE_AGENT));
            const float tl = p - n + MARGIN;
            if (tl > 0.0f) { sum += tl; cnt++; }
        }
#pragma unroll
        for (int off = 32; off; off >>= 1) {
            sum += __shfl_down(sum, off, 64);
            cnt += __shfl_down(cnt, off, 64);
        }
        if (tid == 0) out[0] = (cnt > 0) ? sum / (float)cnt : 0.0f;
    }
#undef STAGE
#undef DSREAD
#undef MFMA3
}

extern "C" void kernel_launch(void* const* d_in, const int* in_sizes, int n_in,
                              void* d_out, int out_size, void* d_ws, size_t ws_size,
                              hipStream_t stream) {
    const float* feats = (const float*)d_in[0];
    const int* labels = (const int*)d_in[1];
    float* out = (float*)d_out;

    unsigned* hp = (unsigned*)d_ws;                                   // 4096 u32
    unsigned* hn = hp + NROWS;                                        // 4096 u32
    unsigned* counter = hn + NROWS;                                   // 1 u32
    unsigned short* fhi = (unsigned short*)((char*)d_ws + 33024);     // 256B-aligned
    unsigned short* flo = fhi + (size_t)NROWS * DIM;

    prep_kernel<<<(NROWS * DIM) / (256 * 4), 256, 0, stream>>>(feats, fhi, flo, hp, hn, counter);
    gram_mine_kernel<<<NBLOCKS, 256, 0, stream>>>(fhi, flo, labels, hp, hn, counter, out);
}